// Round 7
// baseline (259.430 us; speedup 1.0000x reference)
//
#include <hip/hip_runtime.h>
#include <hip/hip_bf16.h>

#define EMBED 384
#define SEQ   1024
#define NBATCH 16
#define NH    6
#define HD    64

typedef __bf16 bf16;
typedef bf16  bf16x8 __attribute__((ext_vector_type(8)));
typedef bf16  bf16x4 __attribute__((ext_vector_type(4)));
typedef bf16  bf16x2 __attribute__((ext_vector_type(2)));
typedef float f32x4  __attribute__((ext_vector_type(4)));
typedef float f32x16 __attribute__((ext_vector_type(16)));
typedef int   i32x4  __attribute__((ext_vector_type(4)));

#define MFMA16(a, b, c) __builtin_amdgcn_mfma_f32_16x16x32_bf16((a), (b), (c), 0, 0, 0)
#define MFMA32(a, b, c) __builtin_amdgcn_mfma_f32_32x32x16_bf16((a), (b), (c), 0, 0, 0)

// q is pre-scaled by this in k_qkv so attention is P = exp2(S) directly
#define QSCALE 0.18033688011112042f  // 0.125 * log2(e)

// ---------------------------------------------------------------------------
// K0: merged prep kernel (unchanged from R6).
//   (a) transpose: x[n][c][s] (f32) -> tok[n][s][c] (bf16) via LDS tile
//   (b) weight cvt: f32 -> bf16 for wqkv & wout
// ---------------------------------------------------------------------------
__global__ __launch_bounds__(256) void k_prep(const float* __restrict__ x,
                                              bf16* __restrict__ tok,
                                              const float* __restrict__ wq,
                                              const float* __restrict__ wo,
                                              bf16* __restrict__ wqb,
                                              bf16* __restrict__ wob) {
    __shared__ bf16 tile[64][66];
    int tid = threadIdx.x;

    const int nqkv = 3 * EMBED * EMBED;   // 442368
    const int nout = EMBED * EMBED;       // 147456
    int fb = blockIdx.x + 16 * (blockIdx.y + 6 * blockIdx.z);
    int ci = (fb * 256 + tid) * 4;
    if (ci < nqkv) {
        float4 v = *reinterpret_cast<const float4*>(wq + ci);
        bf16x4 o = {(bf16)v.x, (bf16)v.y, (bf16)v.z, (bf16)v.w};
        *reinterpret_cast<bf16x4*>(wqb + ci) = o;
    } else {
        int j = ci - nqkv;
        if (j < nout) {
            float4 v = *reinterpret_cast<const float4*>(wo + j);
            bf16x4 o = {(bf16)v.x, (bf16)v.y, (bf16)v.z, (bf16)v.w};
            *reinterpret_cast<bf16x4*>(wob + j) = o;
        }
    }

    int n  = blockIdx.z;
    int s0 = blockIdx.x * 64;
    int c0 = blockIdx.y * 64;

    int sl  = tid & 63;
    int cl0 = tid >> 6;  // 0..3
#pragma unroll
    for (int i = 0; i < 16; ++i) {
        int cl = cl0 + i * 4;
        tile[cl][sl] = (bf16)x[((size_t)n * EMBED + (c0 + cl)) * SEQ + s0 + sl];
    }
    __syncthreads();
    int cl  = tid & 63;
    int sl0 = tid >> 6;
#pragma unroll
    for (int i = 0; i < 16; ++i) {
        int s = sl0 + i * 4;
        tok[((size_t)n * SEQ + (s0 + s)) * EMBED + c0 + cl] = tile[cl][s];
    }
}

// ---------------------------------------------------------------------------
// K1: qkv v12 -- L2-direct, no LDS, no barriers.
//   Per-XCD working set (blocks grouped by bm=b&7 -> XCD): A-slab 16n x 98KB
//   ... wait, per XCD: one bm value, all n: 16 x 98KB? No: A slab per (n,bm)
//   is 98KB; XCD sees its bm across n=0..15 -> 1.57MB + wqkv 0.9MB < 4MB L2.
//   Fragments load straight from global (L1/L2); barrier-drain stalls gone.
// ---------------------------------------------------------------------------
__global__ __launch_bounds__(256) void k_qkv(const bf16* __restrict__ tok,
                                             const bf16* __restrict__ wqkv,
                                             bf16* __restrict__ qout,
                                             bf16* __restrict__ kout,
                                             bf16* __restrict__ vtout) {
    int b    = blockIdx.x;       // 1152 blocks
    int bm   = b & 7;            // 8 s-tiles -> XCD
    int g    = b >> 3;
    int bn   = g % 9;            // 9 o-tiles
    int n    = g / 9;
    int wave = threadIdx.x >> 6;
    int lane = threadIdx.x & 63;
    int row16 = lane & 15;
    int quad  = lane >> 4;
    int sw_base = (wave >> 1) * 64;   // wave row offset within tile
    int ow_base = (wave & 1) * 64;

    const bf16* Ar = tok  + ((size_t)n * SEQ + bm * 128 + sw_base + row16) * EMBED + quad * 8;
    const bf16* Br = wqkv + ((size_t)bn * 128 + ow_base + row16) * EMBED + quad * 8;

    f32x4 acc[4][4] = {};
#pragma unroll 2
    for (int kk = 0; kk < EMBED; kk += 32) {
        bf16x8 af[4], bfr[4];
#pragma unroll
        for (int mt = 0; mt < 4; ++mt)
            af[mt] = *reinterpret_cast<const bf16x8*>(Ar + (size_t)(mt * 16) * EMBED + kk);
#pragma unroll
        for (int nt = 0; nt < 4; ++nt)
            bfr[nt] = *reinterpret_cast<const bf16x8*>(Br + (size_t)(nt * 16) * EMBED + kk);
#pragma unroll
        for (int mt = 0; mt < 4; ++mt)
#pragma unroll
            for (int nt = 0; nt < 4; ++nt)
                acc[mt][nt] = MFMA16(af[mt], bfr[nt], acc[mt][nt]);
    }

    int s_base = bm * 128 + sw_base;
    int o_base = bn * 128 + ow_base;
    int part = (bn * 128) / EMBED;  // o-tile never crosses a part boundary
#pragma unroll
    for (int mt = 0; mt < 4; ++mt)
#pragma unroll
        for (int nt = 0; nt < 4; ++nt) {
            int o   = o_base + nt * 16 + row16;
            int rem = o - part * EMBED;
            int h = rem >> 6;
            int d = rem & 63;
            if (part == 0) {        // q: pre-scale by 0.125*log2(e)
#pragma unroll
                for (int r = 0; r < 4; ++r) {
                    int s = s_base + mt * 16 + quad * 4 + r;
                    qout[(((size_t)n * NH + h) * SEQ + s) * HD + d] =
                        (bf16)(acc[mt][nt][r] * QSCALE);
                }
            } else if (part == 1) { // k
#pragma unroll
                for (int r = 0; r < 4; ++r) {
                    int s = s_base + mt * 16 + quad * 4 + r;
                    kout[(((size_t)n * NH + h) * SEQ + s) * HD + d] = (bf16)acc[mt][nt][r];
                }
            } else {                // vT: 4 consecutive s -> 8B store
                int s = s_base + mt * 16 + quad * 4;
                bf16x4 pack;
#pragma unroll
                for (int r = 0; r < 4; ++r) pack[r] = (bf16)acc[mt][nt][r];
                *reinterpret_cast<bf16x4*>(
                    &vtout[(((size_t)n * NH + h) * HD + d) * SEQ + s]) = pack;
            }
        }
}

// ---------------------------------------------------------------------------
// K2: attention v12 = v10 compute structure, L2/L1-direct K and V fragments.
//   No LDS, no staging, no __syncthreads (guide m168->m169: staging L2-fit
//   K/V is pure overhead). Per XCD (lane8 grouping): 12 heads x 256KB = 3MB
//   K/V working set < 4MB L2; per-body 16KB tiles fit 32KB L1 across the
//   block's 4 waves. kf loaded upfront (QK head of chain); vf issued at
//   tt-start so QK MFMA + softmax (~150cy) hides their latency.
//   Layouts identical to v10 (verified): sacc[r] = P[q=l31][t=crow(r,hi)],
//   PV A-frag via permlane32_swap, oacc[dd][r] = O[q=crow(r,hi)][d=dd*32+l31].
// ---------------------------------------------------------------------------
__global__ __launch_bounds__(256) void k_attn(const bf16* __restrict__ q,
                                              const bf16* __restrict__ kmat,
                                              const bf16* __restrict__ vT,
                                              bf16* __restrict__ ao) {
    int b     = blockIdx.x;      // 768 blocks
    int lane8 = b & 7;           // -> XCD (round-robin heuristic)
    int g     = b >> 3;          // 0..95
    int nh    = (g % 12) * 8 + lane8;   // all qt of one nh share lane8
    int qt    = g / 12;                 // 0..7 q-tiles of 128 rows
    int n = nh / NH, h = nh % NH;

    int wave = threadIdx.x >> 6;       // 0..3
    int lane = threadIdx.x & 63;
    int l31  = lane & 31;
    int hi   = lane >> 5;
    int s_row = qt * 128 + wave * 32;

    const bf16* qh = q    + ((size_t)n * NH + h) * SEQ * HD;
    const bf16* kh = kmat + ((size_t)n * NH + h) * SEQ * HD;
    const bf16* vh = vT   + ((size_t)n * NH + h) * HD * SEQ;

    // Q fragments (B-operand): row j=q=l31, k = kd*16 + hi*8 .. +7
    bf16x8 qfr[4];
#pragma unroll
    for (int kd = 0; kd < 4; ++kd)
        qfr[kd] = *reinterpret_cast<const bf16x8*>(
            qh + (size_t)(s_row + l31) * HD + kd * 16 + hi * 8);

    // per-lane fragment base pointers
    const bf16* krow = kh + (size_t)l31 * HD + hi * 8;          // + t*HD + kd*16
    const bf16* vrow0 = vh + (size_t)l31 * SEQ + hi * 8;        // d = l31
    const bf16* vrow1 = vh + (size_t)(32 + l31) * SEQ + hi * 8; // d = 32+l31

    float lsum = 0.f;
    f32x16 oacc[2] = {};

#pragma unroll 1
    for (int tg = 0; tg < SEQ; tg += 64) {
        // K fragments for both 32-t halves, upfront (head of dep chain)
        bf16x8 kf[2][4];
#pragma unroll
        for (int tt = 0; tt < 2; ++tt)
#pragma unroll
            for (int kd = 0; kd < 4; ++kd)
                kf[tt][kd] = *reinterpret_cast<const bf16x8*>(
                    krow + (size_t)(tg + tt * 32) * HD + kd * 16);

#pragma unroll
        for (int tt = 0; tt < 2; ++tt) {
            // V fragments for this tt (independent of QK -> issued early,
            // latency hidden under QK MFMAs + softmax)
            bf16x8 vfl[2][2];
#pragma unroll
            for (int j = 0; j < 2; ++j) {
                vfl[0][j] = *reinterpret_cast<const bf16x8*>(
                    vrow0 + tg + tt * 32 + j * 16);
                vfl[1][j] = *reinterpret_cast<const bf16x8*>(
                    vrow1 + tg + tt * 32 + j * 16);
            }
            // S = K * Q^T (swapped): sacc[r] = P-pre[q=l31][t=tg+tt*32+crow(r,hi)]
            f32x16 sacc = {0.f, 0.f, 0.f, 0.f, 0.f, 0.f, 0.f, 0.f,
                           0.f, 0.f, 0.f, 0.f, 0.f, 0.f, 0.f, 0.f};
#pragma unroll
            for (int kd = 0; kd < 4; ++kd)
                sacc = MFMA32(kf[tt][kd], qfr[kd], sacc);
            // P = exp2(S); pack pairs to bf16x2 dwords
            int w[8];
#pragma unroll
            for (int i = 0; i < 8; ++i) {
                float e0 = __builtin_amdgcn_exp2f(sacc[2 * i]);
                float e1 = __builtin_amdgcn_exp2f(sacc[2 * i + 1]);
                lsum += e0 + e1;
                bf16x2 pk = {(bf16)e0, (bf16)e1};
                w[i] = __builtin_bit_cast(int, pk);
            }
            // lane<->lane+32 exchange on VALU pipe
            auto s02 = __builtin_amdgcn_permlane32_swap(w[0], w[2], false, false);
            auto s13 = __builtin_amdgcn_permlane32_swap(w[1], w[3], false, false);
            auto s46 = __builtin_amdgcn_permlane32_swap(w[4], w[6], false, false);
            auto s57 = __builtin_amdgcn_permlane32_swap(w[5], w[7], false, false);
            i32x4 a0 = {(int)s02[0], (int)s13[0], (int)s02[1], (int)s13[1]};
            i32x4 a1 = {(int)s46[0], (int)s57[0], (int)s46[1], (int)s57[1]};
            bf16x8 pa0 = __builtin_bit_cast(bf16x8, a0);   // t = +0..15
            bf16x8 pa1 = __builtin_bit_cast(bf16x8, a1);   // t = +16..31
            // O += P*V : A=pa (i=q), B=V^T[d][t-chunk] (j=d)
#pragma unroll
            for (int dd = 0; dd < 2; ++dd) {
                oacc[dd] = MFMA32(pa0, vfl[dd][0], oacc[dd]);
                oacc[dd] = MFMA32(pa1, vfl[dd][1], oacc[dd]);
            }
        }
    }

    // row-sum: lane (q=l31,hi) holds half the t-values of row q
    float tot = lsum + __shfl_xor(lsum, 32, 64);
    float inv = 1.0f / tot;  // valid for q = l31 (both hi halves)

    // store: oacc[dd][r] is O[q = s_row + crow(r,hi)][d = dd*32 + l31]
#pragma unroll
    for (int r = 0; r < 16; ++r) {
        int qp = (r & 3) + 8 * (r >> 2) + 4 * hi;
        float li = __shfl(inv, qp, 64);
        size_t rowoff = ((size_t)n * SEQ + s_row + qp) * EMBED + h * HD;
#pragma unroll
        for (int dd = 0; dd < 2; ++dd)
            ao[rowoff + dd * 32 + l31] = (bf16)(oacc[dd][r] * li);
    }
}

// ---------------------------------------------------------------------------
// K3: proj v12 -- L2-direct, no LDS, no barriers. v11 orientation retained:
//   D[o][s], A = wout rows (i=o), B = ao rows (j=s); contiguous-s f32 stores.
//   Per XCD: ao slabs 1.57MB + wout 0.3MB < 4MB L2.
// ---------------------------------------------------------------------------
__global__ __launch_bounds__(256) void k_proj(const bf16* __restrict__ ao,
                                              const bf16* __restrict__ wout,
                                              const float* __restrict__ bout,
                                              float* __restrict__ out) {
    int b    = blockIdx.x;       // 768 blocks
    int bm   = b & 15;           // 16 s-tiles of 64
    int g    = b >> 4;
    int bn   = g % 3;            // 3 o-tiles
    int n    = g / 3;
    int wave = threadIdx.x >> 6;
    int lane = threadIdx.x & 63;
    int row16 = lane & 15;
    int quad  = lane >> 4;
    int wo_base = (wave & 1) * 64;    // o slab within 128-o tile
    int ws_base = (wave >> 1) * 32;   // s slab within 64-s tile

    const bf16* Wr = wout + ((size_t)bn * 128 + wo_base + row16) * EMBED + quad * 8;
    const bf16* Ar = ao   + ((size_t)n * SEQ + bm * 64 + ws_base + row16) * EMBED + quad * 8;

    f32x4 acc[4][2] = {};   // [om over o][sn over s]
#pragma unroll 2
    for (int kk = 0; kk < EMBED; kk += 32) {
        bf16x8 wf[4], af[2];
#pragma unroll
        for (int om = 0; om < 4; ++om)
            wf[om] = *reinterpret_cast<const bf16x8*>(Wr + (size_t)(om * 16) * EMBED + kk);
#pragma unroll
        for (int sn = 0; sn < 2; ++sn)
            af[sn] = *reinterpret_cast<const bf16x8*>(Ar + (size_t)(sn * 16) * EMBED + kk);
#pragma unroll
        for (int om = 0; om < 4; ++om)
#pragma unroll
            for (int sn = 0; sn < 2; ++sn)
                acc[om][sn] = MFMA16(wf[om], af[sn], acc[om][sn]);
    }

    int o_base = bn * 128 + wo_base;       // + om*16 + quad*4 + r
    int s_base = bm * 64 + ws_base;        // + sn*16 + row16

    float lb[4][4];
#pragma unroll
    for (int om = 0; om < 4; ++om)
#pragma unroll
        for (int r = 0; r < 4; ++r)
            lb[om][r] = bout[o_base + om * 16 + quad * 4 + r];

#pragma unroll
    for (int om = 0; om < 4; ++om)
#pragma unroll
        for (int sn = 0; sn < 2; ++sn)
#pragma unroll
            for (int r = 0; r < 4; ++r) {
                int o = o_base + om * 16 + quad * 4 + r;
                int s = s_base + sn * 16 + row16;
                out[((size_t)n * EMBED + o) * SEQ + s] = acc[om][sn][r] + lb[om][r];
            }
}

// ---------------------------------------------------------------------------
extern "C" void kernel_launch(void* const* d_in, const int* in_sizes, int n_in,
                              void* d_out, int out_size, void* d_ws, size_t ws_size,
                              hipStream_t stream) {
    const float *x = nullptr, *wqkv = nullptr, *wout = nullptr, *bout = nullptr;
    for (int i = 0; i < n_in; ++i) {
        switch (in_sizes[i]) {
            case NBATCH * EMBED * SEQ:   x    = (const float*)d_in[i]; break;  // 6291456
            case 3 * EMBED * EMBED:      wqkv = (const float*)d_in[i]; break;  // 442368
            case EMBED * EMBED:          wout = (const float*)d_in[i]; break;  // 147456
            case EMBED:                  bout = (const float*)d_in[i]; break;  // 384
        }
    }
    float* out = (float*)d_out;

    bf16* ws = (bf16*)d_ws;
    const size_t NE = (size_t)NBATCH * SEQ * EMBED;  // 6.29M elems
    bf16* tok   = ws;
    bf16* q     = ws + NE;
    bf16* k     = ws + 2 * NE;
    bf16* vT    = ws + 3 * NE;
    bf16* ao    = ws + 4 * NE;
    bf16* wqkvb = ws + 5 * NE;
    bf16* woutb = wqkvb + 3 * EMBED * EMBED;

    k_prep<<<dim3(16, 6, 16), 256, 0, stream>>>(x, tok, wqkv, wout, wqkvb, woutb);
    k_qkv<<<dim3(1152), 256, 0, stream>>>(tok, wqkvb, q, k, vT);
    k_attn<<<dim3(768), 256, 0, stream>>>(q, k, vT, ao);
    k_proj<<<dim3(768), 256, 0, stream>>>(ao, woutb, bout, out);
}

// Round 8
// 168.115 us; speedup vs baseline: 1.5432x; 1.5432x over previous
//
#include <hip/hip_runtime.h>
#include <hip/hip_bf16.h>

#define EMBED 384
#define SEQ   1024
#define NBATCH 16
#define NH    6
#define HD    64

typedef __bf16 bf16;
typedef bf16  bf16x8 __attribute__((ext_vector_type(8)));
typedef bf16  bf16x4 __attribute__((ext_vector_type(4)));
typedef bf16  bf16x2 __attribute__((ext_vector_type(2)));
typedef float f32x4  __attribute__((ext_vector_type(4)));
typedef float f32x16 __attribute__((ext_vector_type(16)));
typedef int   i32x4  __attribute__((ext_vector_type(4)));

#define MFMA16(a, b, c) __builtin_amdgcn_mfma_f32_16x16x32_bf16((a), (b), (c), 0, 0, 0)
#define MFMA32(a, b, c) __builtin_amdgcn_mfma_f32_32x32x16_bf16((a), (b), (c), 0, 0, 0)

// q is pre-scaled by this in k_qkv so attention is P = exp2(S) directly
#define QSCALE 0.18033688011112042f  // 0.125 * log2(e)

// async global->LDS, 16B per lane; LDS dst = wave-uniform base + lane*16
__device__ __forceinline__ void gload_lds16(const void* g, void* l) {
    __builtin_amdgcn_global_load_lds(
        (const __attribute__((address_space(1))) void*)g,
        (__attribute__((address_space(3))) void*)l, 16, 0, 0);
}

// ---------------------------------------------------------------------------
// K0: merged prep kernel.
//   (a) transpose: x[n][c][s] (f32) -> tok[n][s][c] (bf16) via LDS tile
//   (b) weight cvt: f32 -> bf16 for wqkv & wout
// ---------------------------------------------------------------------------
__global__ __launch_bounds__(256) void k_prep(const float* __restrict__ x,
                                              bf16* __restrict__ tok,
                                              const float* __restrict__ wq,
                                              const float* __restrict__ wo,
                                              bf16* __restrict__ wqb,
                                              bf16* __restrict__ wob) {
    __shared__ bf16 tile[64][66];
    int tid = threadIdx.x;

    const int nqkv = 3 * EMBED * EMBED;   // 442368
    const int nout = EMBED * EMBED;       // 147456
    int fb = blockIdx.x + 16 * (blockIdx.y + 6 * blockIdx.z);
    int ci = (fb * 256 + tid) * 4;
    if (ci < nqkv) {
        float4 v = *reinterpret_cast<const float4*>(wq + ci);
        bf16x4 o = {(bf16)v.x, (bf16)v.y, (bf16)v.z, (bf16)v.w};
        *reinterpret_cast<bf16x4*>(wqb + ci) = o;
    } else {
        int j = ci - nqkv;
        if (j < nout) {
            float4 v = *reinterpret_cast<const float4*>(wo + j);
            bf16x4 o = {(bf16)v.x, (bf16)v.y, (bf16)v.z, (bf16)v.w};
            *reinterpret_cast<bf16x4*>(wob + j) = o;
        }
    }

    int n  = blockIdx.z;
    int s0 = blockIdx.x * 64;
    int c0 = blockIdx.y * 64;

    int sl  = tid & 63;
    int cl0 = tid >> 6;  // 0..3
#pragma unroll
    for (int i = 0; i < 16; ++i) {
        int cl = cl0 + i * 4;
        tile[cl][sl] = (bf16)x[((size_t)n * EMBED + (c0 + cl)) * SEQ + s0 + sl];
    }
    __syncthreads();
    int cl  = tid & 63;
    int sl0 = tid >> 6;
#pragma unroll
    for (int i = 0; i < 16; ++i) {
        int s = sl0 + i * 4;
        tok[((size_t)n * SEQ + (s0 + s)) * EMBED + c0 + cl] = tile[cl][s];
    }
}

// ---------------------------------------------------------------------------
// K1: qkv (R6 LDS version -- v12's L2-direct variant regressed 2.2x and is
//   reverted). Double-buffered LDS staging, BK=32, manual x2 unroll.
// ---------------------------------------------------------------------------
__global__ __launch_bounds__(256) void k_qkv(const bf16* __restrict__ tok,
                                             const bf16* __restrict__ wqkv,
                                             bf16* __restrict__ qout,
                                             bf16* __restrict__ kout,
                                             bf16* __restrict__ vtout) {
    __shared__ __align__(16) bf16 At[2][128 * 32];  // 8KB each, 64B rows
    __shared__ __align__(16) bf16 Bt[2][128 * 32];

    int b    = blockIdx.x;       // 1152 blocks
    int bm   = b & 7;            // 8 s-tiles -> XCD
    int g    = b >> 3;
    int bn   = g % 9;            // 9 o-tiles
    int n    = g / 9;
    int wave = threadIdx.x >> 6;
    int lane = threadIdx.x & 63;
    int row16 = lane & 15;
    int quad  = lane >> 4;
    int sw_base = (wave >> 1) * 64;   // wave row offset within tile
    int ow_base = (wave & 1) * 64;

    const bf16* Ag = tok  + ((size_t)n * SEQ + bm * 128) * EMBED;
    const bf16* Bg = wqkv + (size_t)bn * 128 * EMBED;

    int srow = lane >> 2;        // 0..15 within 16-row slab
    int scol = (lane & 3) * 8;   // 8 elems = 16B
    const bf16* Abase = Ag + (size_t)(wave * 32 + srow) * EMBED + scol;
    const bf16* Bbase = Bg + (size_t)(wave * 32 + srow) * EMBED + scol;
    bf16* AtW = &At[0][0] + wave * 32 * 32;   // uniform LDS slab base
    bf16* BtW = &Bt[0][0] + wave * 32 * 32;

    auto stage = [&](int kk, int bi) {
        gload_lds16(Abase + kk,               AtW + bi * 128 * 32);
        gload_lds16(Abase + kk + 16 * EMBED,  AtW + bi * 128 * 32 + 16 * 32);
        gload_lds16(Bbase + kk,               BtW + bi * 128 * 32);
        gload_lds16(Bbase + kk + 16 * EMBED,  BtW + bi * 128 * 32 + 16 * 32);
    };

    f32x4 acc[4][4] = {};
    auto gemmstep = [&](const bf16* at, const bf16* bt) {
        bf16x8 af[4], bfr[4];
#pragma unroll
        for (int mt = 0; mt < 4; ++mt)
            af[mt] = *reinterpret_cast<const bf16x8*>(
                at + (sw_base + mt * 16 + row16) * 32 + quad * 8);
#pragma unroll
        for (int nt = 0; nt < 4; ++nt)
            bfr[nt] = *reinterpret_cast<const bf16x8*>(
                bt + (ow_base + nt * 16 + row16) * 32 + quad * 8);
#pragma unroll
        for (int mt = 0; mt < 4; ++mt)
#pragma unroll
            for (int nt = 0; nt < 4; ++nt)
                acc[mt][nt] = MFMA16(af[mt], bfr[nt], acc[mt][nt]);
    };

    stage(0, 0);
#pragma unroll 1
    for (int s2 = 0; s2 < 6; ++s2) {
        int kk = s2 * 64;
        __syncthreads();
        stage(kk + 32, 1);               // step 2*s2+1 <= 11: always valid
        gemmstep(&At[0][0], &Bt[0][0]);
        __syncthreads();
        if (s2 < 5) stage(kk + 64, 0);
        gemmstep(&At[1][0], &Bt[1][0]);
    }

    int s_base = bm * 128 + sw_base;
    int o_base = bn * 128 + ow_base;
    int part = (bn * 128) / EMBED;  // o-tile never crosses a part boundary
#pragma unroll
    for (int mt = 0; mt < 4; ++mt)
#pragma unroll
        for (int nt = 0; nt < 4; ++nt) {
            int o   = o_base + nt * 16 + row16;
            int rem = o - part * EMBED;
            int h = rem >> 6;
            int d = rem & 63;
            if (part == 0) {        // q: pre-scale by 0.125*log2(e)
#pragma unroll
                for (int r = 0; r < 4; ++r) {
                    int s = s_base + mt * 16 + quad * 4 + r;
                    qout[(((size_t)n * NH + h) * SEQ + s) * HD + d] =
                        (bf16)(acc[mt][nt][r] * QSCALE);
                }
            } else if (part == 1) { // k
#pragma unroll
                for (int r = 0; r < 4; ++r) {
                    int s = s_base + mt * 16 + quad * 4 + r;
                    kout[(((size_t)n * NH + h) * SEQ + s) * HD + d] = (bf16)acc[mt][nt][r];
                }
            } else {                // vT: 4 consecutive s -> 8B store
                int s = s_base + mt * 16 + quad * 4;
                bf16x4 pack;
#pragma unroll
                for (int r = 0; r < 4; ++r) pack[r] = (bf16)acc[mt][nt][r];
                *reinterpret_cast<bf16x4*>(
                    &vtout[(((size_t)n * NH + h) * HD + d) * SEQ + s]) = pack;
            }
        }
}

// ---------------------------------------------------------------------------
// K2: attention v13 = v10 compute structure + conflict-free subtiled LDS.
//   R7 post-mortem: L2-direct (v12) regressed 2.2x -> LDS staging essential.
//   v10's row-major+XOR layout had a structural 4-way conflict (32 lanes x
//   16B over 8 chunk slots repeat every 128B row): 3.15M conflict cycles =
//   +33% LDS-pipe time. New layout: 8-row subtiles, chunk-major within:
//     slot(t, c) = (t>>3)*64 + c*8 + (t&7)      [16B slots]
//   Body reads: per-lane off = (l31>>3)*512 + hi*64 + (l31&7)*8 + uniform
//   -> 64 lanes = 8 contiguous 128B bank-rows = ZERO conflict.
//   Staging: gload G covers slots G*64..+63 -> lane l = (row G*8+(l&7),
//   chunk l>>3) -> 8 full 128B lines per gload, coalescing unchanged.
//   Fragment values per lane identical to v10 (index algebra verified).
//   + T5 s_setprio around MFMA clusters (attn +4-7%, m191).
// ---------------------------------------------------------------------------
__global__ __launch_bounds__(256) void k_attn(const bf16* __restrict__ q,
                                              const bf16* __restrict__ kmat,
                                              const bf16* __restrict__ vT,
                                              bf16* __restrict__ ao) {
    __shared__ __align__(16) bf16 ktile[2][4096];   // 8KB per buf, subtiled
    __shared__ __align__(16) bf16 vtile[2][4096];

    int b     = blockIdx.x;      // 768 blocks
    int lane8 = b & 7;           // -> XCD (round-robin heuristic)
    int g     = b >> 3;          // 0..95
    int nh    = (g % 12) * 8 + lane8;   // all qt of one nh share lane8
    int qt    = g / 12;                 // 0..7 q-tiles of 128 rows
    int n = nh / NH, h = nh % NH;

    int wave = threadIdx.x >> 6;       // 0..3
    int lane = threadIdx.x & 63;
    int l31  = lane & 31;
    int hi   = lane >> 5;
    int s_row = qt * 128 + wave * 32;

    const bf16* qh = q    + ((size_t)n * NH + h) * SEQ * HD;
    const bf16* kh = kmat + ((size_t)n * NH + h) * SEQ * HD;
    const bf16* vh = vT   + ((size_t)n * NH + h) * HD * SEQ;

    // Q fragments (B-operand): row j=q=l31, k = kd*16 + hi*8 .. +7
    bf16x8 qfr[4];
#pragma unroll
    for (int kd = 0; kd < 4; ++kd)
        qfr[kd] = *reinterpret_cast<const bf16x8*>(
            qh + (size_t)(s_row + l31) * HD + kd * 16 + hi * 8);

    // staging: wave w stages K t-groups {2w,2w+1} and V d-groups {2w,2w+1}.
    // gload lane l -> (row = group*8 + (l&7), chunk = l>>3): 8 rows x 128B.
    int lm8 = lane & 7, ld8 = lane >> 3;
    const bf16* ksrc = kh + (size_t)(wave * 16 + lm8) * HD + ld8 * 8;   // +t0*HD
    const bf16* vsrc = vh + (size_t)(wave * 16 + lm8) * SEQ + ld8 * 8;  // +t0
    bf16* ktW = &ktile[0][0] + wave * 1024;   // uniform slab base (2 groups)
    bf16* vtW = &vtile[0][0] + wave * 1024;

    auto stage = [&](int t0, int bi) {
        int lb = bi * 4096;
        gload_lds16(ksrc + (size_t)t0 * HD,       ktW + lb);
        gload_lds16(ksrc + (size_t)(t0 + 8) * HD, ktW + lb + 512);
        gload_lds16(vsrc + t0,                    vtW + lb);
        gload_lds16(vsrc + t0 + 8 * SEQ,          vtW + lb + 512);
    };

    // per-lane read base (elements), shared by kf and vf reads
    int rlo = (l31 >> 3) * 512 + hi * 64 + (l31 & 7) * 8;

    float lsum = 0.f;
    f32x16 oacc[2] = {};

    auto body = [&](const bf16* kb, const bf16* vb) {
#pragma unroll
        for (int tt = 0; tt < 2; ++tt) {
            // S = K * Q^T (swapped): sacc[r] = P-pre[q=l31][t = tt*32 + crow(r,hi)]
            f32x16 sacc = {0.f, 0.f, 0.f, 0.f, 0.f, 0.f, 0.f, 0.f,
                           0.f, 0.f, 0.f, 0.f, 0.f, 0.f, 0.f, 0.f};
            __builtin_amdgcn_s_setprio(1);
#pragma unroll
            for (int kd = 0; kd < 4; ++kd) {
                bf16x8 kf = *reinterpret_cast<const bf16x8*>(
                    kb + rlo + tt * 2048 + kd * 128);
                sacc = MFMA32(kf, qfr[kd], sacc);
            }
            __builtin_amdgcn_s_setprio(0);
            // P = exp2(S); pack pairs to bf16x2 dwords
            int w[8];
#pragma unroll
            for (int i = 0; i < 8; ++i) {
                float e0 = __builtin_amdgcn_exp2f(sacc[2 * i]);
                float e1 = __builtin_amdgcn_exp2f(sacc[2 * i + 1]);
                lsum += e0 + e1;
                bf16x2 pk = {(bf16)e0, (bf16)e1};
                w[i] = __builtin_bit_cast(int, pk);
            }
            // lane<->lane+32 exchange on VALU pipe
            auto s02 = __builtin_amdgcn_permlane32_swap(w[0], w[2], false, false);
            auto s13 = __builtin_amdgcn_permlane32_swap(w[1], w[3], false, false);
            auto s46 = __builtin_amdgcn_permlane32_swap(w[4], w[6], false, false);
            auto s57 = __builtin_amdgcn_permlane32_swap(w[5], w[7], false, false);
            i32x4 a0 = {(int)s02[0], (int)s13[0], (int)s02[1], (int)s13[1]};
            i32x4 a1 = {(int)s46[0], (int)s57[0], (int)s46[1], (int)s57[1]};
            bf16x8 pa0 = __builtin_bit_cast(bf16x8, a0);   // t = tt*32 + 0..15
            bf16x8 pa1 = __builtin_bit_cast(bf16x8, a1);   // t = tt*32 + 16..31
            // O += P*V : A=pa (i=q), B=V^T[d][t-chunk] (j=d)
            __builtin_amdgcn_s_setprio(1);
#pragma unroll
            for (int dd = 0; dd < 2; ++dd) {
                bf16x8 vf0 = *reinterpret_cast<const bf16x8*>(
                    vb + rlo + dd * 2048 + tt * 256);
                oacc[dd] = MFMA32(pa0, vf0, oacc[dd]);
                bf16x8 vf1 = *reinterpret_cast<const bf16x8*>(
                    vb + rlo + dd * 2048 + tt * 256 + 128);
                oacc[dd] = MFMA32(pa1, vf1, oacc[dd]);
            }
            __builtin_amdgcn_s_setprio(0);
        }
    };

    stage(0, 0);
#pragma unroll 1
    for (int it2 = 0; it2 < 8; ++it2) {
        int t0 = it2 * 128;
        __syncthreads();
        stage(t0 + 64, 1);               // tile 2*it2+1 <= 15: always valid
        body(&ktile[0][0], &vtile[0][0]);
        __syncthreads();
        if (it2 < 7) stage(t0 + 128, 0);
        body(&ktile[1][0], &vtile[1][0]);
    }

    // row-sum: lane (q=l31,hi) holds half the t-values of row q
    float tot = lsum + __shfl_xor(lsum, 32, 64);
    float inv = 1.0f / tot;  // valid for q = l31 (both hi halves)

    // store: oacc[dd][r] is O[q = s_row + crow(r,hi)][d = dd*32 + l31]
#pragma unroll
    for (int r = 0; r < 16; ++r) {
        int qp = (r & 3) + 8 * (r >> 2) + 4 * hi;
        float li = __shfl(inv, qp, 64);
        size_t rowoff = ((size_t)n * SEQ + s_row + qp) * EMBED + h * HD;
#pragma unroll
        for (int dd = 0; dd < 2; ++dd)
            ao[rowoff + dd * 32 + l31] = (bf16)(oacc[dd][r] * li);
    }
}

// ---------------------------------------------------------------------------
// K3: proj (R6 LDS version, v11 orientation). D[o][s]: A = wout rows (i=o),
//   B = ao rows (j=s); contiguous-s f32 stores.
// ---------------------------------------------------------------------------
__global__ __launch_bounds__(256) void k_proj(const bf16* __restrict__ ao,
                                              const bf16* __restrict__ wout,
                                              const float* __restrict__ bout,
                                              float* __restrict__ out) {
    __shared__ __align__(16) bf16 At[2][64 * 32];    // ao rows, 4KB each
    __shared__ __align__(16) bf16 Bt[2][128 * 32];   // wout rows, 8KB each

    int b    = blockIdx.x;       // 768 blocks
    int bm   = b & 15;           // 16 s-tiles of 64
    int g    = b >> 4;
    int bn   = g % 3;            // 3 o-tiles
    int n    = g / 3;
    int wave = threadIdx.x >> 6;
    int lane = threadIdx.x & 63;
    int row16 = lane & 15;
    int quad  = lane >> 4;
    int wo_base = (wave & 1) * 64;    // o slab within 128-o tile
    int ws_base = (wave >> 1) * 32;   // s slab within 64-s tile

    const bf16* Ag = ao + ((size_t)n * SEQ + bm * 64) * EMBED;

    int srow = lane >> 2;        // 0..15
    int scol = (lane & 3) * 8;
    const bf16* Abase = Ag   + (size_t)(wave * 16 + srow) * EMBED + scol;
    const bf16* Bbase = wout + (size_t)(bn * 128 + wave * 32 + srow) * EMBED + scol;
    bf16* AtW = &At[0][0] + wave * 16 * 32;
    bf16* BtW = &Bt[0][0] + wave * 32 * 32;

    auto stage = [&](int kk, int bi) {
        gload_lds16(Abase + kk,               AtW + bi * 64 * 32);
        gload_lds16(Bbase + kk,               BtW + bi * 128 * 32);
        gload_lds16(Bbase + kk + 16 * EMBED,  BtW + bi * 128 * 32 + 16 * 32);
    };

    f32x4 acc[4][2] = {};   // [om over o][sn over s]
    auto gemmstep = [&](const bf16* at, const bf16* bt) {
        bf16x8 wf[4], af[2];
#pragma unroll
        for (int om = 0; om < 4; ++om)
            wf[om] = *reinterpret_cast<const bf16x8*>(
                bt + (wo_base + om * 16 + row16) * 32 + quad * 8);
#pragma unroll
        for (int sn = 0; sn < 2; ++sn)
            af[sn] = *reinterpret_cast<const bf16x8*>(
                at + (ws_base + sn * 16 + row16) * 32 + quad * 8);
#pragma unroll
        for (int om = 0; om < 4; ++om)
#pragma unroll
            for (int sn = 0; sn < 2; ++sn)
                acc[om][sn] = MFMA16(wf[om], af[sn], acc[om][sn]);
    };

    stage(0, 0);
#pragma unroll 1
    for (int s2 = 0; s2 < 6; ++s2) {
        int kk = s2 * 64;
        __syncthreads();
        stage(kk + 32, 1);
        gemmstep(&At[0][0], &Bt[0][0]);
        __syncthreads();
        if (s2 < 5) stage(kk + 64, 0);
        gemmstep(&At[1][0], &Bt[1][0]);
    }

    int o_base = bn * 128 + wo_base;       // + om*16 + quad*4 + r
    int s_base = bm * 64 + ws_base;        // + sn*16 + row16

    float lb[4][4];
#pragma unroll
    for (int om = 0; om < 4; ++om)
#pragma unroll
        for (int r = 0; r < 4; ++r)
            lb[om][r] = bout[o_base + om * 16 + quad * 4 + r];

#pragma unroll
    for (int om = 0; om < 4; ++om)
#pragma unroll
        for (int sn = 0; sn < 2; ++sn)
#pragma unroll
            for (int r = 0; r < 4; ++r) {
                int o = o_base + om * 16 + quad * 4 + r;
                int s = s_base + sn * 16 + row16;
                out[((size_t)n * EMBED + o) * SEQ + s] = acc[om][sn][r] + lb[om][r];
            }
}

// ---------------------------------------------------------------------------
extern "C" void kernel_launch(void* const* d_in, const int* in_sizes, int n_in,
                              void* d_out, int out_size, void* d_ws, size_t ws_size,
                              hipStream_t stream) {
    const float *x = nullptr, *wqkv = nullptr, *wout = nullptr, *bout = nullptr;
    for (int i = 0; i < n_in; ++i) {
        switch (in_sizes[i]) {
            case NBATCH * EMBED * SEQ:   x    = (const float*)d_in[i]; break;  // 6291456
            case 3 * EMBED * EMBED:      wqkv = (const float*)d_in[i]; break;  // 442368
            case EMBED * EMBED:          wout = (const float*)d_in[i]; break;  // 147456
            case EMBED:                  bout = (const float*)d_in[i]; break;  // 384
        }
    }
    float* out = (float*)d_out;

    bf16* ws = (bf16*)d_ws;
    const size_t NE = (size_t)NBATCH * SEQ * EMBED;  // 6.29M elems
    bf16* tok   = ws;
    bf16* q     = ws + NE;
    bf16* k     = ws + 2 * NE;
    bf16* vT    = ws + 3 * NE;
    bf16* ao    = ws + 4 * NE;
    bf16* wqkvb = ws + 5 * NE;
    bf16* woutb = wqkvb + 3 * EMBED * EMBED;

    k_prep<<<dim3(16, 6, 16), 256, 0, stream>>>(x, tok, wqkv, wout, wqkvb, woutb);
    k_qkv<<<dim3(1152), 256, 0, stream>>>(tok, wqkvb, q, k, vT);
    k_attn<<<dim3(768), 256, 0, stream>>>(q, k, vT, ao);
    k_proj<<<dim3(768), 256, 0, stream>>>(ao, woutb, bout, out);
}

// Round 9
// 163.484 us; speedup vs baseline: 1.5869x; 1.0283x over previous
//
#include <hip/hip_runtime.h>
#include <hip/hip_bf16.h>

#define EMBED 384
#define SEQ   1024
#define NBATCH 16
#define NH    6
#define HD    64

typedef __bf16 bf16;
typedef bf16  bf16x8 __attribute__((ext_vector_type(8)));
typedef bf16  bf16x4 __attribute__((ext_vector_type(4)));
typedef bf16  bf16x2 __attribute__((ext_vector_type(2)));
typedef float f32x4  __attribute__((ext_vector_type(4)));
typedef float f32x16 __attribute__((ext_vector_type(16)));
typedef int   i32x4  __attribute__((ext_vector_type(4)));

#define MFMA16(a, b, c) __builtin_amdgcn_mfma_f32_16x16x32_bf16((a), (b), (c), 0, 0, 0)
#define MFMA32(a, b, c) __builtin_amdgcn_mfma_f32_32x32x16_bf16((a), (b), (c), 0, 0, 0)

// q is pre-scaled by this in k_qkv so attention is P = exp2(S) directly
#define QSCALE 0.18033688011112042f  // 0.125 * log2(e)

// async global->LDS, 16B per lane; LDS dst = wave-uniform base + lane*16
__device__ __forceinline__ void gload_lds16(const void* g, void* l) {
    __builtin_amdgcn_global_load_lds(
        (const __attribute__((address_space(1))) void*)g,
        (__attribute__((address_space(3))) void*)l, 16, 0, 0);
}

// ---------------------------------------------------------------------------
// K0: merged prep kernel.
//   (a) transpose: x[n][c][s] (f32) -> tok[n][s][c] (bf16) via LDS tile
//   (b) weight cvt: f32 -> bf16 for wqkv & wout
// ---------------------------------------------------------------------------
__global__ __launch_bounds__(256) void k_prep(const float* __restrict__ x,
                                              bf16* __restrict__ tok,
                                              const float* __restrict__ wq,
                                              const float* __restrict__ wo,
                                              bf16* __restrict__ wqb,
                                              bf16* __restrict__ wob) {
    __shared__ bf16 tile[64][66];
    int tid = threadIdx.x;

    const int nqkv = 3 * EMBED * EMBED;   // 442368
    const int nout = EMBED * EMBED;       // 147456
    int fb = blockIdx.x + 16 * (blockIdx.y + 6 * blockIdx.z);
    int ci = (fb * 256 + tid) * 4;
    if (ci < nqkv) {
        float4 v = *reinterpret_cast<const float4*>(wq + ci);
        bf16x4 o = {(bf16)v.x, (bf16)v.y, (bf16)v.z, (bf16)v.w};
        *reinterpret_cast<bf16x4*>(wqb + ci) = o;
    } else {
        int j = ci - nqkv;
        if (j < nout) {
            float4 v = *reinterpret_cast<const float4*>(wo + j);
            bf16x4 o = {(bf16)v.x, (bf16)v.y, (bf16)v.z, (bf16)v.w};
            *reinterpret_cast<bf16x4*>(wob + j) = o;
        }
    }

    int n  = blockIdx.z;
    int s0 = blockIdx.x * 64;
    int c0 = blockIdx.y * 64;

    int sl  = tid & 63;
    int cl0 = tid >> 6;  // 0..3
#pragma unroll
    for (int i = 0; i < 16; ++i) {
        int cl = cl0 + i * 4;
        tile[cl][sl] = (bf16)x[((size_t)n * EMBED + (c0 + cl)) * SEQ + s0 + sl];
    }
    __syncthreads();
    int cl  = tid & 63;
    int sl0 = tid >> 6;
#pragma unroll
    for (int i = 0; i < 16; ++i) {
        int s = sl0 + i * 4;
        tok[((size_t)n * SEQ + (s0 + s)) * EMBED + c0 + cl] = tile[cl][s];
    }
}

// ---------------------------------------------------------------------------
// K1: qkv v14 -- 128(s) x 192(o) tile, grid 768 = 256 CUs x 3 exact rounds
//   (was 1152 = 4.5/CU with a half-idle tail). Per wave 64x96 sub-tile:
//   24 MFMA : 10 ds_read per BK=32 step (was 16:8), 1/3 fewer barrier
//   drains. 192 | 384 so an o-tile never crosses a q/k/v part boundary.
//   Same verified staging/LDS/epilogue skeleton as R6.
// ---------------------------------------------------------------------------
__global__ __launch_bounds__(256) void k_qkv(const bf16* __restrict__ tok,
                                             const bf16* __restrict__ wqkv,
                                             bf16* __restrict__ qout,
                                             bf16* __restrict__ kout,
                                             bf16* __restrict__ vtout) {
    __shared__ __align__(16) bf16 At[2][128 * 32];  // 8KB each
    __shared__ __align__(16) bf16 Bt[2][192 * 32];  // 12KB each

    int b    = blockIdx.x;       // 768 blocks
    int bm   = b & 7;            // 8 s-tiles -> XCD
    int g    = b >> 3;
    int bn   = g % 6;            // 6 o-tiles of 192
    int n    = g / 6;
    int wave = threadIdx.x >> 6;
    int lane = threadIdx.x & 63;
    int row16 = lane & 15;
    int quad  = lane >> 4;
    int sw_base = (wave >> 1) * 64;   // wave s-rows within 128-tile
    int ow_base = (wave & 1) * 96;    // wave o-cols within 192-tile

    const bf16* Ag = tok  + ((size_t)n * SEQ + bm * 128) * EMBED;
    const bf16* Bg = wqkv + (size_t)bn * 192 * EMBED;

    int srow = lane >> 2;        // 0..15 within 16-row slab
    int scol = (lane & 3) * 8;   // 8 elems = 16B
    const bf16* Abase = Ag + (size_t)(wave * 32 + srow) * EMBED + scol;
    const bf16* Bbase = Bg + (size_t)(wave * 48 + srow) * EMBED + scol;
    bf16* AtW = &At[0][0] + wave * 32 * 32;   // uniform LDS slab base
    bf16* BtW = &Bt[0][0] + wave * 48 * 32;

    auto stage = [&](int kk, int bi) {
        gload_lds16(Abase + kk,               AtW + bi * 128 * 32);
        gload_lds16(Abase + kk + 16 * EMBED,  AtW + bi * 128 * 32 + 16 * 32);
        gload_lds16(Bbase + kk,               BtW + bi * 192 * 32);
        gload_lds16(Bbase + kk + 16 * EMBED,  BtW + bi * 192 * 32 + 16 * 32);
        gload_lds16(Bbase + kk + 32 * EMBED,  BtW + bi * 192 * 32 + 32 * 32);
    };

    f32x4 acc[4][6] = {};
    auto gemmstep = [&](const bf16* at, const bf16* bt) {
        bf16x8 af[4], bfr[6];
#pragma unroll
        for (int mt = 0; mt < 4; ++mt)
            af[mt] = *reinterpret_cast<const bf16x8*>(
                at + (sw_base + mt * 16 + row16) * 32 + quad * 8);
#pragma unroll
        for (int nt = 0; nt < 6; ++nt)
            bfr[nt] = *reinterpret_cast<const bf16x8*>(
                bt + (ow_base + nt * 16 + row16) * 32 + quad * 8);
#pragma unroll
        for (int mt = 0; mt < 4; ++mt)
#pragma unroll
            for (int nt = 0; nt < 6; ++nt)
                acc[mt][nt] = MFMA16(af[mt], bfr[nt], acc[mt][nt]);
    };

    stage(0, 0);
#pragma unroll 1
    for (int s2 = 0; s2 < 6; ++s2) {
        int kk = s2 * 64;
        __syncthreads();
        stage(kk + 32, 1);               // step 2*s2+1 <= 11: always valid
        gemmstep(&At[0][0], &Bt[0][0]);
        __syncthreads();
        if (s2 < 5) stage(kk + 64, 0);
        gemmstep(&At[1][0], &Bt[1][0]);
    }

    int s_base = bm * 128 + sw_base;
    int o_base = bn * 192 + ow_base;
#pragma unroll
    for (int mt = 0; mt < 4; ++mt)
#pragma unroll
        for (int nt = 0; nt < 6; ++nt) {
            int o    = o_base + nt * 16 + row16;
            int part = o / EMBED;        // constant per (bn,nt) after unroll
            int rem  = o - part * EMBED;
            int h = rem >> 6;
            int d = rem & 63;
            if (part == 0) {        // q: pre-scale by 0.125*log2(e)
#pragma unroll
                for (int r = 0; r < 4; ++r) {
                    int s = s_base + mt * 16 + quad * 4 + r;
                    qout[(((size_t)n * NH + h) * SEQ + s) * HD + d] =
                        (bf16)(acc[mt][nt][r] * QSCALE);
                }
            } else if (part == 1) { // k
#pragma unroll
                for (int r = 0; r < 4; ++r) {
                    int s = s_base + mt * 16 + quad * 4 + r;
                    kout[(((size_t)n * NH + h) * SEQ + s) * HD + d] = (bf16)acc[mt][nt][r];
                }
            } else {                // vT: 4 consecutive s -> 8B store
                int s = s_base + mt * 16 + quad * 4;
                bf16x4 pack;
#pragma unroll
                for (int r = 0; r < 4; ++r) pack[r] = (bf16)acc[mt][nt][r];
                *reinterpret_cast<bf16x4*>(
                    &vtout[(((size_t)n * NH + h) * HD + d) * SEQ + s]) = pack;
            }
        }
}

// ---------------------------------------------------------------------------
// K2: attention v10 EXACT restore (best measured: 42.9us). 32x32 MFMA +
//   swapped QK^T + in-register softmax via permlane32_swap. R8 lesson:
//   the 3.15M bank-conflict cycles are from the global_load_lds WRITE side
//   (196608 gloads x 16cy, exact match) -- read-side relayout (v13) didn't
//   change the counter and regressed staging coalescing. v10 is the local
//   optimum of this structure.
// ---------------------------------------------------------------------------
__global__ __launch_bounds__(256) void k_attn(const bf16* __restrict__ q,
                                              const bf16* __restrict__ kmat,
                                              const bf16* __restrict__ vT,
                                              bf16* __restrict__ ao) {
    __shared__ __align__(16) bf16 ktile[2][64 * 64];   // swizzled [t][d]
    __shared__ __align__(16) bf16 vtile[2][64 * 64];   // swizzled [d][t]

    int b     = blockIdx.x;      // 768 blocks
    int lane8 = b & 7;           // -> XCD (round-robin heuristic)
    int g     = b >> 3;          // 0..95
    int nh    = (g % 12) * 8 + lane8;   // all qt of one nh share lane8
    int qt    = g / 12;                 // 0..7 q-tiles of 128 rows
    int n = nh / NH, h = nh % NH;

    int wave = threadIdx.x >> 6;       // 0..3
    int lane = threadIdx.x & 63;
    int l31  = lane & 31;
    int hi   = lane >> 5;
    int sw5  = l31 & 7;                // read-side swizzle key (row&7)
    int s_row = qt * 128 + wave * 32;

    const bf16* qh = q    + ((size_t)n * NH + h) * SEQ * HD;
    const bf16* kh = kmat + ((size_t)n * NH + h) * SEQ * HD;
    const bf16* vh = vT   + ((size_t)n * NH + h) * HD * SEQ;

    // Q fragments (B-operand): row j=q=l31, k = kd*16 + hi*8 .. +7
    bf16x8 qfr[4];
#pragma unroll
    for (int kd = 0; kd < 4; ++kd)
        qfr[kd] = *reinterpret_cast<const bf16x8*>(
            qh + (size_t)(s_row + l31) * HD + kd * 16 + hi * 8);

    // staging identical to v6: per wave stages 16 rows of K and of V.
    // Pre-swizzled source chunk ck=(lane&7)^(row&7); +8-row slab keeps ck.
    int r0   = wave * 16;
    int srow = r0 + (lane >> 3);
    int ck   = (lane & 7) ^ (srow & 7);
    const bf16* kbase = kh + (size_t)srow * HD + ck * 8;   // +t0*HD per iter
    const bf16* vbase = vh + (size_t)srow * SEQ + ck * 8;  // +t0 per iter
    bf16* ktW = &ktile[0][0] + r0 * 64;    // uniform LDS slab bases
    bf16* vtW = &vtile[0][0] + r0 * 64;

    auto stage = [&](int t0, int bi) {
        int lb = bi * 64 * 64;
        gload_lds16(kbase + (size_t)t0 * HD,           ktW + lb);
        gload_lds16(kbase + (size_t)t0 * HD + 8 * HD,  ktW + lb + 8 * 64);
        gload_lds16(vbase + t0,                        vtW + lb);
        gload_lds16(vbase + t0 + 8 * SEQ,              vtW + lb + 8 * 64);
    };

    float lsum = 0.f;
    f32x16 oacc[2] = {};

    auto body = [&](const bf16* kb, const bf16* vb) {
#pragma unroll
        for (int tt = 0; tt < 2; ++tt) {
            // S = K * Q^T (swapped): sacc[r] = P-pre[q=l31][t = tt*32 + crow(r,hi)]
            f32x16 sacc = {0.f, 0.f, 0.f, 0.f, 0.f, 0.f, 0.f, 0.f,
                           0.f, 0.f, 0.f, 0.f, 0.f, 0.f, 0.f, 0.f};
#pragma unroll
            for (int kd = 0; kd < 4; ++kd) {
                bf16x8 kf = *reinterpret_cast<const bf16x8*>(
                    kb + (tt * 32 + l31) * 64 + (((kd * 2 + hi) ^ sw5) * 8));
                sacc = MFMA32(kf, qfr[kd], sacc);
            }
            // P = exp2(S); pack pairs to bf16x2 dwords
            int w[8];
#pragma unroll
            for (int i = 0; i < 8; ++i) {
                float e0 = __builtin_amdgcn_exp2f(sacc[2 * i]);
                float e1 = __builtin_amdgcn_exp2f(sacc[2 * i + 1]);
                lsum += e0 + e1;
                bf16x2 pk = {(bf16)e0, (bf16)e1};
                w[i] = __builtin_bit_cast(int, pk);
            }
            // lane<->lane+32 exchange on VALU pipe
            auto s02 = __builtin_amdgcn_permlane32_swap(w[0], w[2], false, false);
            auto s13 = __builtin_amdgcn_permlane32_swap(w[1], w[3], false, false);
            auto s46 = __builtin_amdgcn_permlane32_swap(w[4], w[6], false, false);
            auto s57 = __builtin_amdgcn_permlane32_swap(w[5], w[7], false, false);
            i32x4 a0 = {(int)s02[0], (int)s13[0], (int)s02[1], (int)s13[1]};
            i32x4 a1 = {(int)s46[0], (int)s57[0], (int)s46[1], (int)s57[1]};
            bf16x8 pa0 = __builtin_bit_cast(bf16x8, a0);   // t = tt*32 + 0..15
            bf16x8 pa1 = __builtin_bit_cast(bf16x8, a1);   // t = tt*32 + 16..31
            // O += P*V : A=pa (i=q), B=V^T[d][t-chunk] (j=d)
#pragma unroll
            for (int dd = 0; dd < 2; ++dd) {
                bf16x8 vf0 = *reinterpret_cast<const bf16x8*>(
                    vb + (dd * 32 + l31) * 64 + (((tt * 4 + 0 + hi) ^ sw5) * 8));
                oacc[dd] = MFMA32(pa0, vf0, oacc[dd]);
                bf16x8 vf1 = *reinterpret_cast<const bf16x8*>(
                    vb + (dd * 32 + l31) * 64 + (((tt * 4 + 2 + hi) ^ sw5) * 8));
                oacc[dd] = MFMA32(pa1, vf1, oacc[dd]);
            }
        }
    };

    stage(0, 0);
#pragma unroll 1
    for (int it2 = 0; it2 < 8; ++it2) {
        int t0 = it2 * 128;
        __syncthreads();
        stage(t0 + 64, 1);               // tile 2*it2+1 <= 15: always valid
        body(&ktile[0][0], &vtile[0][0]);
        __syncthreads();
        if (it2 < 7) stage(t0 + 128, 0);
        body(&ktile[1][0], &vtile[1][0]);
    }

    // row-sum: lane (q=l31,hi) holds half the t-values of row q
    float tot = lsum + __shfl_xor(lsum, 32, 64);
    float inv = 1.0f / tot;  // valid for q = l31 (both hi halves)

    // store: oacc[dd][r] is O[q = s_row + crow(r,hi)][d = dd*32 + l31]
#pragma unroll
    for (int r = 0; r < 16; ++r) {
        int qp = (r & 3) + 8 * (r >> 2) + 4 * hi;
        float li = __shfl(inv, qp, 64);
        size_t rowoff = ((size_t)n * SEQ + s_row + qp) * EMBED + h * HD;
#pragma unroll
        for (int dd = 0; dd < 2; ++dd)
            ao[rowoff + dd * 32 + l31] = (bf16)(oacc[dd][r] * li);
    }
}

// ---------------------------------------------------------------------------
// K3: proj (R6 LDS version, v11 orientation). D[o][s]: A = wout rows (i=o),
//   B = ao rows (j=s); contiguous-s f32 stores.
// ---------------------------------------------------------------------------
__global__ __launch_bounds__(256) void k_proj(const bf16* __restrict__ ao,
                                              const bf16* __restrict__ wout,
                                              const float* __restrict__ bout,
                                              float* __restrict__ out) {
    __shared__ __align__(16) bf16 At[2][64 * 32];    // ao rows, 4KB each
    __shared__ __align__(16) bf16 Bt[2][128 * 32];   // wout rows, 8KB each

    int b    = blockIdx.x;       // 768 blocks
    int bm   = b & 15;           // 16 s-tiles of 64
    int g    = b >> 4;
    int bn   = g % 3;            // 3 o-tiles
    int n    = g / 3;
    int wave = threadIdx.x >> 6;
    int lane = threadIdx.x & 63;
    int row16 = lane & 15;
    int quad  = lane >> 4;
    int wo_base = (wave & 1) * 64;    // o slab within 128-o tile
    int ws_base = (wave >> 1) * 32;   // s slab within 64-s tile

    const bf16* Ag = ao + ((size_t)n * SEQ + bm * 64) * EMBED;

    int srow = lane >> 2;        // 0..15
    int scol = (lane & 3) * 8;
    const bf16* Abase = Ag   + (size_t)(wave * 16 + srow) * EMBED + scol;
    const bf16* Bbase = wout + (size_t)(bn * 128 + wave * 32 + srow) * EMBED + scol;
    bf16* AtW = &At[0][0] + wave * 16 * 32;
    bf16* BtW = &Bt[0][0] + wave * 32 * 32;

    auto stage = [&](int kk, int bi) {
        gload_lds16(Abase + kk,               AtW + bi * 64 * 32);
        gload_lds16(Bbase + kk,               BtW + bi * 128 * 32);
        gload_lds16(Bbase + kk + 16 * EMBED,  BtW + bi * 128 * 32 + 16 * 32);
    };

    f32x4 acc[4][2] = {};   // [om over o][sn over s]
    auto gemmstep = [&](const bf16* at, const bf16* bt) {
        bf16x8 wf[4], af[2];
#pragma unroll
        for (int om = 0; om < 4; ++om)
            wf[om] = *reinterpret_cast<const bf16x8*>(
                bt + (wo_base + om * 16 + row16) * 32 + quad * 8);
#pragma unroll
        for (int sn = 0; sn < 2; ++sn)
            af[sn] = *reinterpret_cast<const bf16x8*>(
                at + (ws_base + sn * 16 + row16) * 32 + quad * 8);
#pragma unroll
        for (int om = 0; om < 4; ++om)
#pragma unroll
            for (int sn = 0; sn < 2; ++sn)
                acc[om][sn] = MFMA16(wf[om], af[sn], acc[om][sn]);
    };

    stage(0, 0);
#pragma unroll 1
    for (int s2 = 0; s2 < 6; ++s2) {
        int kk = s2 * 64;
        __syncthreads();
        stage(kk + 32, 1);
        gemmstep(&At[0][0], &Bt[0][0]);
        __syncthreads();
        if (s2 < 5) stage(kk + 64, 0);
        gemmstep(&At[1][0], &Bt[1][0]);
    }

    int o_base = bn * 128 + wo_base;       // + om*16 + quad*4 + r
    int s_base = bm * 64 + ws_base;        // + sn*16 + row16

    float lb[4][4];
#pragma unroll
    for (int om = 0; om < 4; ++om)
#pragma unroll
        for (int r = 0; r < 4; ++r)
            lb[om][r] = bout[o_base + om * 16 + quad * 4 + r];

#pragma unroll
    for (int om = 0; om < 4; ++om)
#pragma unroll
        for (int sn = 0; sn < 2; ++sn)
#pragma unroll
            for (int r = 0; r < 4; ++r) {
                int o = o_base + om * 16 + quad * 4 + r;
                int s = s_base + sn * 16 + row16;
                out[((size_t)n * EMBED + o) * SEQ + s] = acc[om][sn][r] + lb[om][r];
            }
}

// ---------------------------------------------------------------------------
extern "C" void kernel_launch(void* const* d_in, const int* in_sizes, int n_in,
                              void* d_out, int out_size, void* d_ws, size_t ws_size,
                              hipStream_t stream) {
    const float *x = nullptr, *wqkv = nullptr, *wout = nullptr, *bout = nullptr;
    for (int i = 0; i < n_in; ++i) {
        switch (in_sizes[i]) {
            case NBATCH * EMBED * SEQ:   x    = (const float*)d_in[i]; break;  // 6291456
            case 3 * EMBED * EMBED:      wqkv = (const float*)d_in[i]; break;  // 442368
            case EMBED * EMBED:          wout = (const float*)d_in[i]; break;  // 147456
            case EMBED:                  bout = (const float*)d_in[i]; break;  // 384
        }
    }
    float* out = (float*)d_out;

    bf16* ws = (bf16*)d_ws;
    const size_t NE = (size_t)NBATCH * SEQ * EMBED;  // 6.29M elems
    bf16* tok   = ws;
    bf16* q     = ws + NE;
    bf16* k     = ws + 2 * NE;
    bf16* vT    = ws + 3 * NE;
    bf16* ao    = ws + 4 * NE;
    bf16* wqkvb = ws + 5 * NE;
    bf16* woutb = wqkvb + 3 * EMBED * EMBED;

    k_prep<<<dim3(16, 6, 16), 256, 0, stream>>>(x, tok, wqkv, wout, wqkvb, woutb);
    k_qkv<<<dim3(768), 256, 0, stream>>>(tok, wqkvb, q, k, vT);
    k_attn<<<dim3(768), 256, 0, stream>>>(q, k, vT, ao);
    k_proj<<<dim3(768), 256, 0, stream>>>(ao, woutb, bout, out);
}

// Round 10
// 158.643 us; speedup vs baseline: 1.6353x; 1.0305x over previous
//
#include <hip/hip_runtime.h>
#include <hip/hip_bf16.h>

#define EMBED 384
#define SEQ   1024
#define NBATCH 16
#define NH    6
#define HD    64

typedef __bf16 bf16;
typedef bf16  bf16x8 __attribute__((ext_vector_type(8)));
typedef bf16  bf16x4 __attribute__((ext_vector_type(4)));
typedef bf16  bf16x2 __attribute__((ext_vector_type(2)));
typedef float f32x4  __attribute__((ext_vector_type(4)));
typedef float f32x16 __attribute__((ext_vector_type(16)));
typedef int   i32x4  __attribute__((ext_vector_type(4)));

#define MFMA16(a, b, c) __builtin_amdgcn_mfma_f32_16x16x32_bf16((a), (b), (c), 0, 0, 0)
#define MFMA32(a, b, c) __builtin_amdgcn_mfma_f32_32x32x16_bf16((a), (b), (c), 0, 0, 0)

// q is pre-scaled by this in k_qkv so attention is P = exp2(S) directly
#define QSCALE 0.18033688011112042f  // 0.125 * log2(e)

// async global->LDS, 16B per lane; LDS dst = wave-uniform base + lane*16
__device__ __forceinline__ void gload_lds16(const void* g, void* l) {
    __builtin_amdgcn_global_load_lds(
        (const __attribute__((address_space(1))) void*)g,
        (__attribute__((address_space(3))) void*)l, 16, 0, 0);
}

// ---------------------------------------------------------------------------
// K0: merged prep kernel.
//   (a) transpose: x[n][c][s] (f32) -> tok[n][s][c] (bf16) via LDS tile
//   (b) weight cvt: f32 -> bf16 for wqkv & wout
// ---------------------------------------------------------------------------
__global__ __launch_bounds__(256) void k_prep(const float* __restrict__ x,
                                              bf16* __restrict__ tok,
                                              const float* __restrict__ wq,
                                              const float* __restrict__ wo,
                                              bf16* __restrict__ wqb,
                                              bf16* __restrict__ wob) {
    __shared__ bf16 tile[64][66];
    int tid = threadIdx.x;

    const int nqkv = 3 * EMBED * EMBED;   // 442368
    const int nout = EMBED * EMBED;       // 147456
    int fb = blockIdx.x + 16 * (blockIdx.y + 6 * blockIdx.z);
    int ci = (fb * 256 + tid) * 4;
    if (ci < nqkv) {
        float4 v = *reinterpret_cast<const float4*>(wq + ci);
        bf16x4 o = {(bf16)v.x, (bf16)v.y, (bf16)v.z, (bf16)v.w};
        *reinterpret_cast<bf16x4*>(wqb + ci) = o;
    } else {
        int j = ci - nqkv;
        if (j < nout) {
            float4 v = *reinterpret_cast<const float4*>(wo + j);
            bf16x4 o = {(bf16)v.x, (bf16)v.y, (bf16)v.z, (bf16)v.w};
            *reinterpret_cast<bf16x4*>(wob + j) = o;
        }
    }

    int n  = blockIdx.z;
    int s0 = blockIdx.x * 64;
    int c0 = blockIdx.y * 64;

    int sl  = tid & 63;
    int cl0 = tid >> 6;  // 0..3
#pragma unroll
    for (int i = 0; i < 16; ++i) {
        int cl = cl0 + i * 4;
        tile[cl][sl] = (bf16)x[((size_t)n * EMBED + (c0 + cl)) * SEQ + s0 + sl];
    }
    __syncthreads();
    int cl  = tid & 63;
    int sl0 = tid >> 6;
#pragma unroll
    for (int i = 0; i < 16; ++i) {
        int s = sl0 + i * 4;
        tok[((size_t)n * SEQ + (s0 + s)) * EMBED + c0 + cl] = tile[cl][s];
    }
}

// ---------------------------------------------------------------------------
// K1: qkv v14 -- 128(s) x 192(o) tile, grid 768 (measured neutral vs 1152;
//   kept for the exact-3-rounds dispatch). Double-buffered LDS, BK=32.
// ---------------------------------------------------------------------------
__global__ __launch_bounds__(256) void k_qkv(const bf16* __restrict__ tok,
                                             const bf16* __restrict__ wqkv,
                                             bf16* __restrict__ qout,
                                             bf16* __restrict__ kout,
                                             bf16* __restrict__ vtout) {
    __shared__ __align__(16) bf16 At[2][128 * 32];  // 8KB each
    __shared__ __align__(16) bf16 Bt[2][192 * 32];  // 12KB each

    int b    = blockIdx.x;       // 768 blocks
    int bm   = b & 7;            // 8 s-tiles -> XCD
    int g    = b >> 3;
    int bn   = g % 6;            // 6 o-tiles of 192
    int n    = g / 6;
    int wave = threadIdx.x >> 6;
    int lane = threadIdx.x & 63;
    int row16 = lane & 15;
    int quad  = lane >> 4;
    int sw_base = (wave >> 1) * 64;   // wave s-rows within 128-tile
    int ow_base = (wave & 1) * 96;    // wave o-cols within 192-tile

    const bf16* Ag = tok  + ((size_t)n * SEQ + bm * 128) * EMBED;
    const bf16* Bg = wqkv + (size_t)bn * 192 * EMBED;

    int srow = lane >> 2;        // 0..15 within 16-row slab
    int scol = (lane & 3) * 8;   // 8 elems = 16B
    const bf16* Abase = Ag + (size_t)(wave * 32 + srow) * EMBED + scol;
    const bf16* Bbase = Bg + (size_t)(wave * 48 + srow) * EMBED + scol;
    bf16* AtW = &At[0][0] + wave * 32 * 32;   // uniform LDS slab base
    bf16* BtW = &Bt[0][0] + wave * 48 * 32;

    auto stage = [&](int kk, int bi) {
        gload_lds16(Abase + kk,               AtW + bi * 128 * 32);
        gload_lds16(Abase + kk + 16 * EMBED,  AtW + bi * 128 * 32 + 16 * 32);
        gload_lds16(Bbase + kk,               BtW + bi * 192 * 32);
        gload_lds16(Bbase + kk + 16 * EMBED,  BtW + bi * 192 * 32 + 16 * 32);
        gload_lds16(Bbase + kk + 32 * EMBED,  BtW + bi * 192 * 32 + 32 * 32);
    };

    f32x4 acc[4][6] = {};
    auto gemmstep = [&](const bf16* at, const bf16* bt) {
        bf16x8 af[4], bfr[6];
#pragma unroll
        for (int mt = 0; mt < 4; ++mt)
            af[mt] = *reinterpret_cast<const bf16x8*>(
                at + (sw_base + mt * 16 + row16) * 32 + quad * 8);
#pragma unroll
        for (int nt = 0; nt < 6; ++nt)
            bfr[nt] = *reinterpret_cast<const bf16x8*>(
                bt + (ow_base + nt * 16 + row16) * 32 + quad * 8);
#pragma unroll
        for (int mt = 0; mt < 4; ++mt)
#pragma unroll
            for (int nt = 0; nt < 6; ++nt)
                acc[mt][nt] = MFMA16(af[mt], bfr[nt], acc[mt][nt]);
    };

    stage(0, 0);
#pragma unroll 1
    for (int s2 = 0; s2 < 6; ++s2) {
        int kk = s2 * 64;
        __syncthreads();
        stage(kk + 32, 1);               // step 2*s2+1 <= 11: always valid
        gemmstep(&At[0][0], &Bt[0][0]);
        __syncthreads();
        if (s2 < 5) stage(kk + 64, 0);
        gemmstep(&At[1][0], &Bt[1][0]);
    }

    int s_base = bm * 128 + sw_base;
    int o_base = bn * 192 + ow_base;
#pragma unroll
    for (int mt = 0; mt < 4; ++mt)
#pragma unroll
        for (int nt = 0; nt < 6; ++nt) {
            int o    = o_base + nt * 16 + row16;
            int part = o / EMBED;        // constant per (bn,nt) after unroll
            int rem  = o - part * EMBED;
            int h = rem >> 6;
            int d = rem & 63;
            if (part == 0) {        // q: pre-scale by 0.125*log2(e)
#pragma unroll
                for (int r = 0; r < 4; ++r) {
                    int s = s_base + mt * 16 + quad * 4 + r;
                    qout[(((size_t)n * NH + h) * SEQ + s) * HD + d] =
                        (bf16)(acc[mt][nt][r] * QSCALE);
                }
            } else if (part == 1) { // k
#pragma unroll
                for (int r = 0; r < 4; ++r) {
                    int s = s_base + mt * 16 + quad * 4 + r;
                    kout[(((size_t)n * NH + h) * SEQ + s) * HD + d] = (bf16)acc[mt][nt][r];
                }
            } else {                // vT: 4 consecutive s -> 8B store
                int s = s_base + mt * 16 + quad * 4;
                bf16x4 pack;
#pragma unroll
                for (int r = 0; r < 4; ++r) pack[r] = (bf16)acc[mt][nt][r];
                *reinterpret_cast<bf16x4*>(
                    &vtout[(((size_t)n * NH + h) * HD + d) * SEQ + s]) = pack;
            }
        }
}

// ---------------------------------------------------------------------------
// K2: attention v15 = v10 per-wave structure x 2 wave-groups split on t.
//   R9 diagnosis: no pipe exceeds ~15us but kernel takes 43 -> stall-bound
//   with ~1.2 resident blocks/CU (occ 15%). v9 datum: 512-thr blocks force
//   8 waves on-CU (occ 31%). v15: 512 thr; partner waves (w, w+4) own the
//   SAME 32 q-rows, each processes HALF the t-range (0-511 / 512-1023) with
//   private K/V double-buffers (LDS 64KB). Per-wave bodies halve (8 vs 16);
//   body code byte-identical to v10. Epilogue: group1 writes partial
//   oacc/lsum to LDS ([idx][lane], conflict-free), barrier, group0 adds
//   lane-wise (identical lane mapping) and does the v10 normalize+store.
//   Grid stays 768; barrier pattern uniform across all 8 waves.
// ---------------------------------------------------------------------------
__global__ __launch_bounds__(512) void k_attn(const bf16* __restrict__ q,
                                              const bf16* __restrict__ kmat,
                                              const bf16* __restrict__ vT,
                                              bf16* __restrict__ ao) {
    __shared__ __align__(16) bf16 ktile[2][2][4096];   // [grp][buf] 16KB/grp
    __shared__ __align__(16) bf16 vtile[2][2][4096];

    int b     = blockIdx.x;      // 768 blocks
    int lane8 = b & 7;           // -> XCD (round-robin heuristic)
    int g     = b >> 3;          // 0..95
    int nh    = (g % 12) * 8 + lane8;   // all qt of one nh share lane8
    int qt    = g / 12;                 // 0..7 q-tiles of 128 rows
    int n = nh / NH, h = nh % NH;

    int wave = threadIdx.x >> 6;       // 0..7
    int grp  = wave >> 2;              // t-range group
    int wv   = wave & 3;               // wave within group
    int lane = threadIdx.x & 63;
    int l31  = lane & 31;
    int hi   = lane >> 5;
    int sw5  = l31 & 7;                // read-side swizzle key (row&7)
    int s_row = qt * 128 + wv * 32;    // partner waves share q-rows
    int tbase = grp * 512;             // group's t-range base

    const bf16* qh = q    + ((size_t)n * NH + h) * SEQ * HD;
    const bf16* kh = kmat + ((size_t)n * NH + h) * SEQ * HD;
    const bf16* vh = vT   + ((size_t)n * NH + h) * HD * SEQ;

    // Q fragments (B-operand): row j=q=l31, k = kd*16 + hi*8 .. +7
    bf16x8 qfr[4];
#pragma unroll
    for (int kd = 0; kd < 4; ++kd)
        qfr[kd] = *reinterpret_cast<const bf16x8*>(
            qh + (size_t)(s_row + l31) * HD + kd * 16 + hi * 8);

    // staging (v10 scheme per group): wave wv stages 16 rows of K and V.
    // Pre-swizzled source chunk ck=(lane&7)^(row&7); +8-row slab keeps ck.
    int r0   = wv * 16;
    int srow = r0 + (lane >> 3);
    int ck   = (lane & 7) ^ (srow & 7);
    const bf16* kbase = kh + ((size_t)tbase + srow) * HD + ck * 8;  // +t0*HD
    const bf16* vbase = vh + (size_t)srow * SEQ + tbase + ck * 8;   // +t0
    bf16* ktW = &ktile[grp][0][0] + r0 * 64;   // uniform LDS slab bases
    bf16* vtW = &vtile[grp][0][0] + r0 * 64;

    auto stage = [&](int t0, int bi) {
        int lb = bi * 4096;
        gload_lds16(kbase + (size_t)t0 * HD,           ktW + lb);
        gload_lds16(kbase + (size_t)t0 * HD + 8 * HD,  ktW + lb + 8 * 64);
        gload_lds16(vbase + t0,                        vtW + lb);
        gload_lds16(vbase + t0 + 8 * SEQ,              vtW + lb + 8 * 64);
    };

    float lsum = 0.f;
    f32x16 oacc[2] = {};

    auto body = [&](const bf16* kb, const bf16* vb) {
#pragma unroll
        for (int tt = 0; tt < 2; ++tt) {
            // S = K * Q^T (swapped): sacc[r] = P-pre[q=l31][t = tt*32 + crow(r,hi)]
            f32x16 sacc = {0.f, 0.f, 0.f, 0.f, 0.f, 0.f, 0.f, 0.f,
                           0.f, 0.f, 0.f, 0.f, 0.f, 0.f, 0.f, 0.f};
#pragma unroll
            for (int kd = 0; kd < 4; ++kd) {
                bf16x8 kf = *reinterpret_cast<const bf16x8*>(
                    kb + (tt * 32 + l31) * 64 + (((kd * 2 + hi) ^ sw5) * 8));
                sacc = MFMA32(kf, qfr[kd], sacc);
            }
            // P = exp2(S); pack pairs to bf16x2 dwords
            int w[8];
#pragma unroll
            for (int i = 0; i < 8; ++i) {
                float e0 = __builtin_amdgcn_exp2f(sacc[2 * i]);
                float e1 = __builtin_amdgcn_exp2f(sacc[2 * i + 1]);
                lsum += e0 + e1;
                bf16x2 pk = {(bf16)e0, (bf16)e1};
                w[i] = __builtin_bit_cast(int, pk);
            }
            // lane<->lane+32 exchange on VALU pipe
            auto s02 = __builtin_amdgcn_permlane32_swap(w[0], w[2], false, false);
            auto s13 = __builtin_amdgcn_permlane32_swap(w[1], w[3], false, false);
            auto s46 = __builtin_amdgcn_permlane32_swap(w[4], w[6], false, false);
            auto s57 = __builtin_amdgcn_permlane32_swap(w[5], w[7], false, false);
            i32x4 a0 = {(int)s02[0], (int)s13[0], (int)s02[1], (int)s13[1]};
            i32x4 a1 = {(int)s46[0], (int)s57[0], (int)s46[1], (int)s57[1]};
            bf16x8 pa0 = __builtin_bit_cast(bf16x8, a0);   // t = tt*32 + 0..15
            bf16x8 pa1 = __builtin_bit_cast(bf16x8, a1);   // t = tt*32 + 16..31
            // O += P*V : A=pa (i=q), B=V^T[d][t-chunk] (j=d)
#pragma unroll
            for (int dd = 0; dd < 2; ++dd) {
                bf16x8 vf0 = *reinterpret_cast<const bf16x8*>(
                    vb + (dd * 32 + l31) * 64 + (((tt * 4 + 0 + hi) ^ sw5) * 8));
                oacc[dd] = MFMA32(pa0, vf0, oacc[dd]);
                bf16x8 vf1 = *reinterpret_cast<const bf16x8*>(
                    vb + (dd * 32 + l31) * 64 + (((tt * 4 + 2 + hi) ^ sw5) * 8));
                oacc[dd] = MFMA32(pa1, vf1, oacc[dd]);
            }
        }
    };

    // each group walks its 512-t range: 4 iters x 2 bodies = 8 tiles of 64
    stage(0, 0);
#pragma unroll 1
    for (int it2 = 0; it2 < 4; ++it2) {
        int t0 = it2 * 128;
        __syncthreads();
        stage(t0 + 64, 1);               // max t0+64 = 448: always valid
        body(&ktile[grp][0][0], &vtile[grp][0][0]);
        __syncthreads();
        if (it2 < 3) stage(t0 + 128, 0);
        body(&ktile[grp][1][0], &vtile[grp][1][0]);
    }

    // cross-group combine: group1's partials -> LDS -> group0 adds.
    __syncthreads();
    float* ox = reinterpret_cast<float*>(&vtile[0][0][0]);  // 8192 floats
    float* ls = reinterpret_cast<float*>(&ktile[0][0][0]);  // 256 floats used
    if (grp == 1) {
        int base = wv * 2048 + lane;    // [idx][lane]: conflict-free
#pragma unroll
        for (int dd = 0; dd < 2; ++dd)
#pragma unroll
            for (int r = 0; r < 16; ++r)
                ox[base + (dd * 16 + r) * 64] = oacc[dd][r];
        ls[wv * 64 + lane] = lsum;
    }
    __syncthreads();
    if (grp == 0) {
        int base = wv * 2048 + lane;
#pragma unroll
        for (int dd = 0; dd < 2; ++dd)
#pragma unroll
            for (int r = 0; r < 16; ++r)
                oacc[dd][r] += ox[base + (dd * 16 + r) * 64];
        lsum += ls[wv * 64 + lane];

        // row-sum: lane (q=l31,hi) holds half the t-values of row q
        float tot = lsum + __shfl_xor(lsum, 32, 64);
        float inv = 1.0f / tot;  // valid for q = l31 (both hi halves)

        // store: oacc[dd][r] is O[q = s_row + crow(r,hi)][d = dd*32 + l31]
#pragma unroll
        for (int r = 0; r < 16; ++r) {
            int qp = (r & 3) + 8 * (r >> 2) + 4 * hi;
            float li = __shfl(inv, qp, 64);
            size_t rowoff = ((size_t)n * SEQ + s_row + qp) * EMBED + h * HD;
#pragma unroll
            for (int dd = 0; dd < 2; ++dd)
                ao[rowoff + dd * 32 + l31] = (bf16)(oacc[dd][r] * li);
        }
    }
}

// ---------------------------------------------------------------------------
// K3: proj (R6 LDS version, v11 orientation). D[o][s]: A = wout rows (i=o),
//   B = ao rows (j=s); contiguous-s f32 stores.
// ---------------------------------------------------------------------------
__global__ __launch_bounds__(256) void k_proj(const bf16* __restrict__ ao,
                                              const bf16* __restrict__ wout,
                                              const float* __restrict__ bout,
                                              float* __restrict__ out) {
    __shared__ __align__(16) bf16 At[2][64 * 32];    // ao rows, 4KB each
    __shared__ __align__(16) bf16 Bt[2][128 * 32];   // wout rows, 8KB each

    int b    = blockIdx.x;       // 768 blocks
    int bm   = b & 15;           // 16 s-tiles of 64
    int g    = b >> 4;
    int bn   = g % 3;            // 3 o-tiles
    int n    = g / 3;
    int wave = threadIdx.x >> 6;
    int lane = threadIdx.x & 63;
    int row16 = lane & 15;
    int quad  = lane >> 4;
    int wo_base = (wave & 1) * 64;    // o slab within 128-o tile
    int ws_base = (wave >> 1) * 32;   // s slab within 64-s tile

    const bf16* Ag = ao + ((size_t)n * SEQ + bm * 64) * EMBED;

    int srow = lane >> 2;        // 0..15
    int scol = (lane & 3) * 8;
    const bf16* Abase = Ag   + (size_t)(wave * 16 + srow) * EMBED + scol;
    const bf16* Bbase = wout + (size_t)(bn * 128 + wave * 32 + srow) * EMBED + scol;
    bf16* AtW = &At[0][0] + wave * 16 * 32;
    bf16* BtW = &Bt[0][0] + wave * 32 * 32;

    auto stage = [&](int kk, int bi) {
        gload_lds16(Abase + kk,               AtW + bi * 64 * 32);
        gload_lds16(Bbase + kk,               BtW + bi * 128 * 32);
        gload_lds16(Bbase + kk + 16 * EMBED,  BtW + bi * 128 * 32 + 16 * 32);
    };

    f32x4 acc[4][2] = {};   // [om over o][sn over s]
    auto gemmstep = [&](const bf16* at, const bf16* bt) {
        bf16x8 wf[4], af[2];
#pragma unroll
        for (int om = 0; om < 4; ++om)
            wf[om] = *reinterpret_cast<const bf16x8*>(
                bt + (wo_base + om * 16 + row16) * 32 + quad * 8);
#pragma unroll
        for (int sn = 0; sn < 2; ++sn)
            af[sn] = *reinterpret_cast<const bf16x8*>(
                at + (ws_base + sn * 16 + row16) * 32 + quad * 8);
#pragma unroll
        for (int om = 0; om < 4; ++om)
#pragma unroll
            for (int sn = 0; sn < 2; ++sn)
                acc[om][sn] = MFMA16(wf[om], af[sn], acc[om][sn]);
    };

    stage(0, 0);
#pragma unroll 1
    for (int s2 = 0; s2 < 6; ++s2) {
        int kk = s2 * 64;
        __syncthreads();
        stage(kk + 32, 1);
        gemmstep(&At[0][0], &Bt[0][0]);
        __syncthreads();
        if (s2 < 5) stage(kk + 64, 0);
        gemmstep(&At[1][0], &Bt[1][0]);
    }

    int o_base = bn * 128 + wo_base;       // + om*16 + quad*4 + r
    int s_base = bm * 64 + ws_base;        // + sn*16 + row16

    float lb[4][4];
#pragma unroll
    for (int om = 0; om < 4; ++om)
#pragma unroll
        for (int r = 0; r < 4; ++r)
            lb[om][r] = bout[o_base + om * 16 + quad * 4 + r];

#pragma unroll
    for (int om = 0; om < 4; ++om)
#pragma unroll
        for (int sn = 0; sn < 2; ++sn)
#pragma unroll
            for (int r = 0; r < 4; ++r) {
                int o = o_base + om * 16 + quad * 4 + r;
                int s = s_base + sn * 16 + row16;
                out[((size_t)n * EMBED + o) * SEQ + s] = acc[om][sn][r] + lb[om][r];
            }
}

// ---------------------------------------------------------------------------
extern "C" void kernel_launch(void* const* d_in, const int* in_sizes, int n_in,
                              void* d_out, int out_size, void* d_ws, size_t ws_size,
                              hipStream_t stream) {
    const float *x = nullptr, *wqkv = nullptr, *wout = nullptr, *bout = nullptr;
    for (int i = 0; i < n_in; ++i) {
        switch (in_sizes[i]) {
            case NBATCH * EMBED * SEQ:   x    = (const float*)d_in[i]; break;  // 6291456
            case 3 * EMBED * EMBED:      wqkv = (const float*)d_in[i]; break;  // 442368
            case EMBED * EMBED:          wout = (const float*)d_in[i]; break;  // 147456
            case EMBED:                  bout = (const float*)d_in[i]; break;  // 384
        }
    }
    float* out = (float*)d_out;

    bf16* ws = (bf16*)d_ws;
    const size_t NE = (size_t)NBATCH * SEQ * EMBED;  // 6.29M elems
    bf16* tok   = ws;
    bf16* q     = ws + NE;
    bf16* k     = ws + 2 * NE;
    bf16* vT    = ws + 3 * NE;
    bf16* ao    = ws + 4 * NE;
    bf16* wqkvb = ws + 5 * NE;
    bf16* woutb = wqkvb + 3 * EMBED * EMBED;

    k_prep<<<dim3(16, 6, 16), 256, 0, stream>>>(x, tok, wqkv, wout, wqkvb, woutb);
    k_qkv<<<dim3(768), 256, 0, stream>>>(tok, wqkvb, q, k, vT);
    k_attn<<<dim3(768), 512, 0, stream>>>(q, k, vT, ao);
    k_proj<<<dim3(768), 256, 0, stream>>>(ao, woutb, bout, out);
}